// Round 5
// baseline (765.704 us; speedup 1.0000x reference)
//
#include <hip/hip_runtime.h>
#include <hip/hip_bf16.h>

typedef unsigned short u16;
typedef float f32x4 __attribute__((ext_vector_type(4)));
typedef __bf16 bf16x8 __attribute__((ext_vector_type(8)));

#define BB 4
#define SS 2048
#define DD 1024
#define HH 16
#define HDD 64
#define MM (BB*SS)   // 8192

#define NEG_BIG (-3.0e38f)

__device__ __forceinline__ float bf2f(u16 u){
    union { unsigned int i; float f; } v; v.i = ((unsigned int)u) << 16; return v.f;
}
__device__ __forceinline__ u16 f2bf(float f){
    union { float f; unsigned int i; } v; v.f = f;
    unsigned int i = v.i;
    return (u16)((i + 0x7FFFu + ((i >> 16) & 1u)) >> 16);
}

// ---- R5: on-device input-dtype detection ----
// Even-index u16 words of a bf16 tensor of N(0,1) data have exponent field in
// [110,134] with prob ~1. For an fp32 buffer those words are raw mantissa bits
// (uniform) -> ~10%. 64-lane ballot makes the flag deterministic & uniform.
__device__ __forceinline__ bool detect_f32(const void* xraw){
    const u16* x = (const u16*)xraw;
    const int lane = threadIdx.x & 63;
    const u16 wv = x[2 * lane];
    const int e = (wv >> 7) & 0xFF;
    const bool inr = (e >= 110) && (e <= 134);
    const unsigned long long m = __ballot(inr);
    return __popcll(m) < 32;   // few in-range -> mantissa junk -> fp32
}

__device__ __forceinline__ float ldf(const void* p, size_t i, bool isf){
    return isf ? ((const float*)p)[i] : bf2f(((const u16*)p)[i]);
}

// ---------------- GEMM core: C[128,128] tile of A[M,K] @ W[N,K]^T ----------------
// A,W dtype selected at runtime (fp32 or bf16); LDS tiles always bf16.
__device__ __forceinline__ void gemm_core(const void* A, const void* W,
                                          bool a_f32, bool w_f32,
                                          f32x4 (&acc)[4][4],
                                          u16* At, u16* Bt,
                                          int m0, int n0, int tid)
{
    const int lane = tid & 63, w = tid >> 6;
    const int quad = lane >> 4, l15 = lane & 15;
    const int wm = w >> 1, wn = w & 1;

    for (int k0 = 0; k0 < DD; k0 += 32) {
        __syncthreads();   // previous iter's LDS reads done before restaging
        // 128 rows x 32 elems per tile; 256 threads -> 2 slots of 8 elems each
        #pragma unroll
        for (int it = 0; it < 2; ++it) {
            const int c = tid + it * 256;
            const int row = c >> 2, cc = (c & 3) * 8;
            const size_t goff = (size_t)(m0 + row) * DD + k0 + cc;
            if (a_f32) {
                const float* Af = (const float*)A;
                const float4 u0 = *(const float4*)&Af[goff];
                const float4 u1 = *(const float4*)&Af[goff + 4];
                u16 t[8] = { f2bf(u0.x), f2bf(u0.y), f2bf(u0.z), f2bf(u0.w),
                             f2bf(u1.x), f2bf(u1.y), f2bf(u1.z), f2bf(u1.w) };
                *(uint4*)&At[row * 32 + cc] = *(const uint4*)t;
            } else {
                *(uint4*)&At[row * 32 + cc] = *(const uint4*)&((const u16*)A)[goff];
            }
            const size_t woff = (size_t)(n0 + row) * DD + k0 + cc;
            if (w_f32) {
                const float* Wf = (const float*)W;
                const float4 u0 = *(const float4*)&Wf[woff];
                const float4 u1 = *(const float4*)&Wf[woff + 4];
                u16 t[8] = { f2bf(u0.x), f2bf(u0.y), f2bf(u0.z), f2bf(u0.w),
                             f2bf(u1.x), f2bf(u1.y), f2bf(u1.z), f2bf(u1.w) };
                *(uint4*)&Bt[row * 32 + cc] = *(const uint4*)t;
            } else {
                *(uint4*)&Bt[row * 32 + cc] = *(const uint4*)&((const u16*)W)[woff];
            }
        }
        __syncthreads();
        bf16x8 af[4], bfr[4];
        #pragma unroll
        for (int i = 0; i < 4; ++i)
            af[i] = *(const bf16x8*)&At[(wm * 64 + i * 16 + l15) * 32 + quad * 8];
        #pragma unroll
        for (int j = 0; j < 4; ++j)
            bfr[j] = *(const bf16x8*)&Bt[(wn * 64 + j * 16 + l15) * 32 + quad * 8];
        #pragma unroll
        for (int i = 0; i < 4; ++i)
            #pragma unroll
            for (int j = 0; j < 4; ++j)
                acc[i][j] = __builtin_amdgcn_mfma_f32_16x16x32_bf16(af[i], bfr[j], acc[i][j], 0, 0, 0);
    }
}

// QKV projection: z selects q/k/v; output scattered to [B,H,S,HD] (bf16 ws)
__global__ __launch_bounds__(256, 2) void gemm_qkv_k(
    const void* __restrict__ x,
    const void* __restrict__ Wq, const void* __restrict__ bq,
    const void* __restrict__ Wk, const void* __restrict__ bk,
    const void* __restrict__ Wv, const void* __restrict__ bv,
    u16* __restrict__ Q, u16* __restrict__ K, u16* __restrict__ V)
{
    __shared__ alignas(16) u16 At[128 * 32];
    __shared__ alignas(16) u16 Bt[128 * 32];
    const bool isf = detect_f32(x);
    const int tid = threadIdx.x, lane = tid & 63, w = tid >> 6;
    const int quad = lane >> 4, l15 = lane & 15;
    const int wm = w >> 1, wn = w & 1;
    const int z = blockIdx.z;
    const void* Wm = z == 0 ? Wq : (z == 1 ? Wk : Wv);
    const void* bias = z == 0 ? bq : (z == 1 ? bk : bv);
    u16* Out = z == 0 ? Q : (z == 1 ? K : V);
    const int m0 = blockIdx.x * 128, n0 = blockIdx.y * 128;

    f32x4 acc[4][4];
    #pragma unroll
    for (int i = 0; i < 4; ++i)
        #pragma unroll
        for (int j = 0; j < 4; ++j) acc[i][j] = (f32x4)(0.0f);

    gemm_core(x, Wm, isf, isf, acc, At, Bt, m0, n0, tid);

    float bs[4];
    #pragma unroll
    for (int j = 0; j < 4; ++j) bs[j] = ldf(bias, n0 + wn * 64 + j * 16 + l15, isf);

    const int b = m0 / SS;                       // 128 | 2048 -> tile within one b
    const int h = (n0 + wn * 64) / HDD;          // wave-uniform head
    const size_t base = ((size_t)(b * HH + h)) * SS * HDD;
    #pragma unroll
    for (int i = 0; i < 4; ++i) {
        #pragma unroll
        for (int r = 0; r < 4; ++r) {
            const int s = (m0 % SS) + wm * 64 + i * 16 + quad * 4 + r;
            #pragma unroll
            for (int j = 0; j < 4; ++j) {
                const int hd = j * 16 + l15;
                Out[base + (size_t)s * HDD + hd] = f2bf(acc[i][j][r] + bs[j]);
            }
        }
    }
}

// Output projection: A (ws) is always bf16; W/bias + out dtype per flag
__global__ __launch_bounds__(256, 2) void gemm_out_k(
    const void* __restrict__ xdet,
    const u16* __restrict__ A, const void* __restrict__ Wo,
    const void* __restrict__ bo, void* __restrict__ Out)
{
    __shared__ alignas(16) u16 At[128 * 32];
    __shared__ alignas(16) u16 Bt[128 * 32];
    const bool isf = detect_f32(xdet);
    const int tid = threadIdx.x, lane = tid & 63, w = tid >> 6;
    const int quad = lane >> 4, l15 = lane & 15;
    const int wm = w >> 1, wn = w & 1;
    const int m0 = blockIdx.x * 128, n0 = blockIdx.y * 128;

    f32x4 acc[4][4];
    #pragma unroll
    for (int i = 0; i < 4; ++i)
        #pragma unroll
        for (int j = 0; j < 4; ++j) acc[i][j] = (f32x4)(0.0f);

    gemm_core(A, Wo, false, isf, acc, At, Bt, m0, n0, tid);

    float bs[4];
    #pragma unroll
    for (int j = 0; j < 4; ++j) bs[j] = ldf(bo, n0 + wn * 64 + j * 16 + l15, isf);

    #pragma unroll
    for (int i = 0; i < 4; ++i) {
        #pragma unroll
        for (int r = 0; r < 4; ++r) {
            const int m = m0 + wm * 64 + i * 16 + quad * 4 + r;
            #pragma unroll
            for (int j = 0; j < 4; ++j) {
                const int n = n0 + wn * 64 + j * 16 + l15;
                const float v = acc[i][j][r] + bs[j];
                if (isf) ((float*)Out)[(size_t)m * DD + n] = v;
                else     ((u16*)Out)[(size_t)m * DD + n] = f2bf(v);
            }
        }
    }
}

// ---------------- Flash attention (bf16 ws in/out — unchanged) ----------------
#define QT 128
#define KT 64
#define LDP 72   // padded LDS row stride (elements)

__global__ __launch_bounds__(256, 2) void attn_k(
    const u16* __restrict__ Q, const u16* __restrict__ K,
    const u16* __restrict__ V, const int* __restrict__ mask,
    u16* __restrict__ AO)
{
    __shared__ alignas(16) u16 Qs[QT * LDP];
    __shared__ alignas(16) u16 Ks[KT * LDP];
    __shared__ alignas(16) u16 Vs[HDD * LDP];
    __shared__ alignas(16) u16 Ps[QT * LDP];

    const int tid = threadIdx.x, lane = tid & 63, w = tid >> 6;
    const int quad = lane >> 4, l15 = lane & 15;
    const int qt = (int)(gridDim.x - 1 - blockIdx.x);   // heavy tiles dispatch first
    const int bh = blockIdx.y;
    const int b = bh >> 4, h = bh & 15;
    const int q0 = qt * QT;
    const size_t hoff = (size_t)bh * SS * HDD;
    const u16* Qh = Q + hoff;
    const u16* Kh = K + hoff;
    const u16* Vh = V + hoff;

    for (int c = tid; c < QT * 8; c += 256) {
        const int row = c >> 3, cc = c & 7;
        *(uint4*)&Qs[row * LDP + cc * 8] = *(const uint4*)&Qh[(size_t)(q0 + row) * HDD + cc * 8];
    }

    float m_run[2][4], l_run[2][4];
    f32x4 o[2][4];
    #pragma unroll
    for (int i = 0; i < 2; ++i)
        #pragma unroll
        for (int r = 0; r < 4; ++r) { m_run[i][r] = -1e30f; l_run[i][r] = 0.f; }
    #pragma unroll
    for (int i = 0; i < 2; ++i)
        #pragma unroll
        for (int j = 0; j < 4; ++j) o[i][j] = (f32x4)(0.0f);

    const int nkt = (q0 + QT) / KT;
    const float scale = 0.125f;

    for (int kt = 0; kt < nkt; ++kt) {
        const int kt0 = kt * KT;
        __syncthreads();

        for (int c = tid; c < 512; c += 256) {
            const int row = c >> 3, cc = c & 7;
            *(uint4*)&Ks[row * LDP + cc * 8] = *(const uint4*)&Kh[(size_t)(kt0 + row) * HDD + cc * 8];
        }
        for (int idx = tid; idx < KT * HDD; idx += 256) {
            const int kpos = idx >> 6, hd = idx & 63;
            Vs[hd * LDP + kpos] = Vh[(size_t)(kt0 + kpos) * HDD + hd];
        }
        int mk[4];
        #pragma unroll
        for (int j = 0; j < 4; ++j) mk[j] = mask[b * SS + kt0 + j * 16 + l15];
        __syncthreads();

        f32x4 sc[2][4];
        #pragma unroll
        for (int i = 0; i < 2; ++i)
            #pragma unroll
            for (int j = 0; j < 4; ++j) sc[i][j] = (f32x4)(0.0f);
        #pragma unroll
        for (int ks = 0; ks < 2; ++ks) {
            bf16x8 aq[2], bk4[4];
            #pragma unroll
            for (int i = 0; i < 2; ++i)
                aq[i] = *(const bf16x8*)&Qs[(w * 32 + i * 16 + l15) * LDP + ks * 32 + quad * 8];
            #pragma unroll
            for (int j = 0; j < 4; ++j)
                bk4[j] = *(const bf16x8*)&Ks[(j * 16 + l15) * LDP + ks * 32 + quad * 8];
            #pragma unroll
            for (int i = 0; i < 2; ++i)
                #pragma unroll
                for (int j = 0; j < 4; ++j)
                    sc[i][j] = __builtin_amdgcn_mfma_f32_16x16x32_bf16(aq[i], bk4[j], sc[i][j], 0, 0, 0);
        }

        #pragma unroll
        for (int i = 0; i < 2; ++i) {
            #pragma unroll
            for (int r = 0; r < 4; ++r) {
                const int lrow = w * 32 + i * 16 + quad * 4 + r;
                const int grow = q0 + lrow;
                float sv[4];
                float mx = NEG_BIG;
                #pragma unroll
                for (int j = 0; j < 4; ++j) {
                    float s = sc[i][j][r] * scale;
                    const int gcol = kt0 + j * 16 + l15;
                    if (gcol > grow) s = NEG_BIG;
                    if (mk[j] == 0) s = -1e9f;
                    sv[j] = s;
                    mx = fmaxf(mx, s);
                }
                #pragma unroll
                for (int d = 1; d < 16; d <<= 1) mx = fmaxf(mx, __shfl_xor(mx, d, 64));
                const float nm = fmaxf(m_run[i][r], mx);
                const float alpha = __expf(m_run[i][r] - nm);
                m_run[i][r] = nm;
                float rs = 0.f;
                #pragma unroll
                for (int j = 0; j < 4; ++j) {
                    const float p = __expf(sv[j] - nm);
                    rs += p;
                    Ps[lrow * LDP + j * 16 + l15] = f2bf(p);
                }
                #pragma unroll
                for (int d = 1; d < 16; d <<= 1) rs += __shfl_xor(rs, d, 64);
                l_run[i][r] = l_run[i][r] * alpha + rs;
                #pragma unroll
                for (int j = 0; j < 4; ++j) o[i][j][r] *= alpha;
            }
        }
        __syncthreads();

        #pragma unroll
        for (int ks = 0; ks < 2; ++ks) {
            bf16x8 ap[2], bv4[4];
            #pragma unroll
            for (int i = 0; i < 2; ++i)
                ap[i] = *(const bf16x8*)&Ps[(w * 32 + i * 16 + l15) * LDP + ks * 32 + quad * 8];
            #pragma unroll
            for (int j = 0; j < 4; ++j)
                bv4[j] = *(const bf16x8*)&Vs[(j * 16 + l15) * LDP + ks * 32 + quad * 8];
            #pragma unroll
            for (int i = 0; i < 2; ++i)
                #pragma unroll
                for (int j = 0; j < 4; ++j)
                    o[i][j] = __builtin_amdgcn_mfma_f32_16x16x32_bf16(ap[i], bv4[j], o[i][j], 0, 0, 0);
        }
    }

    #pragma unroll
    for (int i = 0; i < 2; ++i) {
        #pragma unroll
        for (int r = 0; r < 4; ++r) {
            const float l = l_run[i][r];
            const float inv = (l > 0.f) ? (1.f / l) : 0.f;
            const int s = q0 + w * 32 + i * 16 + quad * 4 + r;
            const size_t rb = ((size_t)(b * SS + s)) * DD + h * HDD;
            #pragma unroll
            for (int j = 0; j < 4; ++j)
                AO[rb + j * 16 + l15] = f2bf(o[i][j][r] * inv);
        }
    }
}

extern "C" void kernel_launch(void* const* d_in, const int* in_sizes, int n_in,
                              void* d_out, int out_size, void* d_ws, size_t ws_size,
                              hipStream_t stream)
{
    // Input-order mapping via in_sizes (mask has B*S=8192 elements in dict order).
    const bool dict_order = (in_sizes[1] == BB * SS);

    const void* x;  const int* mask;
    const void *Wq, *bq, *Wk, *bk, *Wv, *bv, *Wo, *bo;
    x = d_in[0];
    if (dict_order) {
        mask = (const int*)d_in[1];
        Wq = d_in[2]; bq = d_in[3];
        Wk = d_in[4]; bk = d_in[5];
        Wv = d_in[6]; bv = d_in[7];
        Wo = d_in[8]; bo = d_in[9];
    } else {
        Wq = d_in[1]; bq = d_in[2];
        Wk = d_in[3]; bk = d_in[4];
        Wv = d_in[5]; bv = d_in[6];
        Wo = d_in[7]; bo = d_in[8];
        mask = (const int*)d_in[9];
    }

    u16* ws = (u16*)d_ws;
    const size_t NE = (size_t)MM * DD;            // 8388608 elements per [M,D] buffer
    const size_t need = 4 * NE * sizeof(u16);     // 64 MiB
    if (ws_size < need) return;                   // diagnostic guard (proven not to fire in R4)

    u16* Qb = ws;
    u16* Kb = ws + NE;
    u16* Vb = ws + 2 * NE;
    u16* Ab = ws + 3 * NE;

    dim3 blk(256);
    gemm_qkv_k<<<dim3(MM / 128, DD / 128, 3), blk, 0, stream>>>(
        x, Wq, bq, Wk, bk, Wv, bv, Qb, Kb, Vb);
    attn_k<<<dim3(SS / QT, BB * HH), blk, 0, stream>>>(Qb, Kb, Vb, mask, Ab);
    gemm_out_k<<<dim3(MM / 128, DD / 128), blk, 0, stream>>>(x, Ab, Wo, bo, d_out);
}

// Round 6
// 374.838 us; speedup vs baseline: 2.0428x; 2.0428x over previous
//
#include <hip/hip_runtime.h>
#include <hip/hip_bf16.h>

typedef unsigned short u16;
typedef float f32x4 __attribute__((ext_vector_type(4)));
typedef __bf16 bf16x8 __attribute__((ext_vector_type(8)));

#define BB 4
#define SS 2048
#define DD 1024
#define HH 16
#define HDD 64
#define MM (BB*SS)   // 8192

__device__ __forceinline__ u16 f2bf(float f){
    union { float f; unsigned int i; } v; v.f = f;
    unsigned int i = v.i;
    return (u16)((i + 0x7FFFu + ((i >> 16) & 1u)) >> 16);
}
__device__ __forceinline__ ushort2 pk2(float a, float b){
    union { __hip_bfloat162 h; ushort2 u; } v;
    float2 t; t.x = a; t.y = b;
    v.h = __float22bfloat162_rn(t);
    return v.u;
}
__device__ __forceinline__ ushort4 pk4(float a, float b, float c, float d){
    ushort2 lo = pk2(a, b), hi = pk2(c, d);
    ushort4 r; r.x = lo.x; r.y = lo.y; r.z = hi.x; r.w = hi.y;
    return r;
}

// ---------------- x fp32 -> bf16 pre-convert ----------------
__global__ __launch_bounds__(256) void cvt_k(const float* __restrict__ src,
                                             u16* __restrict__ dst)
{
    const size_t i = ((size_t)blockIdx.x * 256 + threadIdx.x) * 8;
    const float4 a = *(const float4*)&src[i];
    const float4 b = *(const float4*)&src[i + 4];
    ushort4 lo = pk4(a.x, a.y, a.z, a.w);
    ushort4 hi = pk4(b.x, b.y, b.z, b.w);
    uint4 o;
    o.x = (unsigned)lo.x | ((unsigned)lo.y << 16);
    o.y = (unsigned)lo.z | ((unsigned)lo.w << 16);
    o.z = (unsigned)hi.x | ((unsigned)hi.y << 16);
    o.w = (unsigned)hi.z | ((unsigned)hi.w << 16);
    *(uint4*)&dst[i] = o;
}

// ---------------- GEMM core: C[128,128] tile of A_bf16[M,K] @ W_f32[N,K]^T ----------------
__device__ __forceinline__ void gemm_core(const u16* __restrict__ A,
                                          const float* __restrict__ W,
                                          f32x4 (&acc)[4][4],
                                          u16* At, u16* Bt,
                                          int m0, int n0, int tid)
{
    const int lane = tid & 63, w = tid >> 6;
    const int quad = lane >> 4, l15 = lane & 15;
    const int wm = w >> 1, wn = w & 1;

    for (int k0 = 0; k0 < DD; k0 += 32) {
        __syncthreads();
        #pragma unroll
        for (int it = 0; it < 2; ++it) {
            const int c = tid + it * 256;
            const int row = c >> 2, cc = (c & 3) * 8;
            *(uint4*)&At[row * 32 + cc] =
                *(const uint4*)&A[(size_t)(m0 + row) * DD + k0 + cc];
            const size_t woff = (size_t)(n0 + row) * DD + k0 + cc;
            const float4 u0 = *(const float4*)&W[woff];
            const float4 u1 = *(const float4*)&W[woff + 4];
            ushort4 lo = pk4(u0.x, u0.y, u0.z, u0.w);
            ushort4 hi = pk4(u1.x, u1.y, u1.z, u1.w);
            uint4 o;
            o.x = (unsigned)lo.x | ((unsigned)lo.y << 16);
            o.y = (unsigned)lo.z | ((unsigned)lo.w << 16);
            o.z = (unsigned)hi.x | ((unsigned)hi.y << 16);
            o.w = (unsigned)hi.z | ((unsigned)hi.w << 16);
            *(uint4*)&Bt[row * 32 + cc] = o;
        }
        __syncthreads();
        bf16x8 af[4], bfr[4];
        #pragma unroll
        for (int i = 0; i < 4; ++i)
            af[i] = *(const bf16x8*)&At[(wm * 64 + i * 16 + l15) * 32 + quad * 8];
        #pragma unroll
        for (int j = 0; j < 4; ++j)
            bfr[j] = *(const bf16x8*)&Bt[(wn * 64 + j * 16 + l15) * 32 + quad * 8];
        #pragma unroll
        for (int i = 0; i < 4; ++i)
            #pragma unroll
            for (int j = 0; j < 4; ++j)
                acc[i][j] = __builtin_amdgcn_mfma_f32_16x16x32_bf16(af[i], bfr[j], acc[i][j], 0, 0, 0);
    }
}

// QKV projection: z selects q/k/v; output scattered to [B,H,S,HD] (bf16)
__global__ __launch_bounds__(256, 4) void gemm_qkv_k(
    const u16* __restrict__ x,
    const float* __restrict__ Wq, const float* __restrict__ bq,
    const float* __restrict__ Wk, const float* __restrict__ bk,
    const float* __restrict__ Wv, const float* __restrict__ bv,
    u16* __restrict__ Q, u16* __restrict__ K, u16* __restrict__ V)
{
    __shared__ alignas(16) u16 At[128 * 32];
    __shared__ alignas(16) u16 Bt[128 * 32];
    const int tid = threadIdx.x, lane = tid & 63, w = tid >> 6;
    const int quad = lane >> 4, l15 = lane & 15;
    const int wm = w >> 1, wn = w & 1;
    const int z = blockIdx.z;
    const float* Wm = z == 0 ? Wq : (z == 1 ? Wk : Wv);
    const float* bias = z == 0 ? bq : (z == 1 ? bk : bv);
    u16* Out = z == 0 ? Q : (z == 1 ? K : V);
    const int m0 = blockIdx.x * 128, n0 = blockIdx.y * 128;

    f32x4 acc[4][4];
    #pragma unroll
    for (int i = 0; i < 4; ++i)
        #pragma unroll
        for (int j = 0; j < 4; ++j) acc[i][j] = (f32x4)(0.0f);

    gemm_core(x, Wm, acc, At, Bt, m0, n0, tid);

    float bs[4];
    #pragma unroll
    for (int j = 0; j < 4; ++j) bs[j] = bias[n0 + wn * 64 + j * 16 + l15];

    const int b = m0 / SS;
    const int h = (n0 + wn * 64) / HDD;
    const size_t base = ((size_t)(b * HH + h)) * SS * HDD;
    #pragma unroll
    for (int i = 0; i < 4; ++i) {
        #pragma unroll
        for (int r = 0; r < 4; ++r) {
            const int s = (m0 % SS) + wm * 64 + i * 16 + quad * 4 + r;
            #pragma unroll
            for (int j = 0; j < 4; ++j) {
                const int hd = j * 16 + l15;
                Out[base + (size_t)s * HDD + hd] = f2bf(acc[i][j][r] + bs[j]);
            }
        }
    }
}

// Output projection: A bf16 [M,K], Wo fp32, out fp32 [M,N]
__global__ __launch_bounds__(256, 4) void gemm_out_k(
    const u16* __restrict__ A, const float* __restrict__ Wo,
    const float* __restrict__ bo, float* __restrict__ Out)
{
    __shared__ alignas(16) u16 At[128 * 32];
    __shared__ alignas(16) u16 Bt[128 * 32];
    const int tid = threadIdx.x, lane = tid & 63, w = tid >> 6;
    const int quad = lane >> 4, l15 = lane & 15;
    const int wm = w >> 1, wn = w & 1;
    const int m0 = blockIdx.x * 128, n0 = blockIdx.y * 128;

    f32x4 acc[4][4];
    #pragma unroll
    for (int i = 0; i < 4; ++i)
        #pragma unroll
        for (int j = 0; j < 4; ++j) acc[i][j] = (f32x4)(0.0f);

    gemm_core(A, Wo, acc, At, Bt, m0, n0, tid);

    float bs[4];
    #pragma unroll
    for (int j = 0; j < 4; ++j) bs[j] = bo[n0 + wn * 64 + j * 16 + l15];

    #pragma unroll
    for (int i = 0; i < 4; ++i) {
        #pragma unroll
        for (int r = 0; r < 4; ++r) {
            const int m = m0 + wm * 64 + i * 16 + quad * 4 + r;
            #pragma unroll
            for (int j = 0; j < 4; ++j) {
                const int n = n0 + wn * 64 + j * 16 + l15;
                Out[(size_t)m * DD + n] = acc[i][j][r] + bs[j];
            }
        }
    }
}

// ---------------- Flash attention, S^T/O^T formulation ----------------
// S^T = K Q^T puts q-rows on lane&15: row stats = in-register reduce + 2 swizzles
// (was 8 swizzle-steps x 8 rows = 64/iter). O^T = V^T P^T keeps alpha/l per-lane
// aligned with the accumulator. Q B-frags preloaded to regs; Qs LDS reused as Ps.
#define QT 128
#define KT 64
#define LDP 72    // Q/P row stride (elements)
#define LDPV 66   // Vs row stride (elements)

__global__ __launch_bounds__(256, 4) void attn_k(
    const u16* __restrict__ Q, const u16* __restrict__ K,
    const u16* __restrict__ V, const int* __restrict__ mask,
    u16* __restrict__ AO)
{
    __shared__ alignas(16) u16 QPs[QT * LDP];   // 18432 B: Q tile, then P tile
    __shared__ alignas(16) u16 Ks[KT * LDP];    //  9216 B
    __shared__ alignas(16) u16 Vs[HDD * LDPV];  //  8448 B  [hd][kpos]
    __shared__ float padf[KT];                  //   256 B
    // total 36352 B -> 4 blocks/CU

    const int tid = threadIdx.x, lane = tid & 63, w = tid >> 6;
    const int quad = lane >> 4, l15 = lane & 15;
    const int qt = (int)(gridDim.x - 1 - blockIdx.x);   // heavy tiles first
    const int bh = blockIdx.y;
    const int b = bh >> 4, h = bh & 15;
    const int q0 = qt * QT;
    const size_t hoff = (size_t)bh * SS * HDD;
    const u16* Qh = Q + hoff;
    const u16* Kh = K + hoff;
    const u16* Vh = V + hoff;

    // stage Q tile, then preload this wave's B-fragments into registers
    for (int c = tid; c < QT * 8; c += 256) {
        const int row = c >> 3, cc = c & 7;
        *(uint4*)&QPs[row * LDP + cc * 8] = *(const uint4*)&Qh[(size_t)(q0 + row) * HDD + cc * 8];
    }
    __syncthreads();
    bf16x8 bQ[2][2];
    #pragma unroll
    for (int j = 0; j < 2; ++j)
        #pragma unroll
        for (int ks = 0; ks < 2; ++ks)
            bQ[j][ks] = *(const bf16x8*)&QPs[(w * 32 + j * 16 + l15) * LDP + ks * 32 + quad * 8];
    // QPs is now free per-wave (wave w only touches rows w*32..w*32+31 below).

    float m_run[2] = { -1e30f, -1e30f };
    float l_run[2] = { 0.f, 0.f };     // per-quad partial sums
    f32x4 o[4][2];                     // O^T: o[i'][j], hd tile i', qrow tile j
    #pragma unroll
    for (int i = 0; i < 4; ++i)
        #pragma unroll
        for (int j = 0; j < 2; ++j) o[i][j] = (f32x4)(0.0f);

    const int nkt = (q0 + QT) / KT;
    const float scale = 0.125f;        // HD^-0.5

    for (int kt = 0; kt < nkt; ++kt) {
        const int kt0 = kt * KT;
        __syncthreads();   // prior iter's Ks/Vs reads complete

        if (tid < 128) {
            // Ks [kpos][hd]: 512 uint4 / 128 threads
            #pragma unroll
            for (int it = 0; it < 4; ++it) {
                const int c = tid + it * 128;
                const int row = c >> 3, cc = c & 7;
                *(uint4*)&Ks[row * LDP + cc * 8] = *(const uint4*)&Kh[(size_t)(kt0 + row) * HDD + cc * 8];
            }
        } else {
            // Vs [hd][kpos]: vectorized transpose, 4 kpos packed per b64 write
            const int t = tid - 128;
            const int kq = t >> 3;            // 0..15 -> kpos 4*kq..+3
            const int c0 = (t & 7) * 8;       // hd chunk
            uint4 r0 = *(const uint4*)&Vh[(size_t)(kt0 + kq * 4 + 0) * HDD + c0];
            uint4 r1 = *(const uint4*)&Vh[(size_t)(kt0 + kq * 4 + 1) * HDD + c0];
            uint4 r2 = *(const uint4*)&Vh[(size_t)(kt0 + kq * 4 + 2) * HDD + c0];
            uint4 r3 = *(const uint4*)&Vh[(size_t)(kt0 + kq * 4 + 3) * HDD + c0];
            const u16* e0 = (const u16*)&r0;
            const u16* e1 = (const u16*)&r1;
            const u16* e2 = (const u16*)&r2;
            const u16* e3 = (const u16*)&r3;
            #pragma unroll
            for (int e = 0; e < 8; ++e) {
                ushort4 pkv; pkv.x = e0[e]; pkv.y = e1[e]; pkv.z = e2[e]; pkv.w = e3[e];
                *(ushort4*)&Vs[(c0 + e) * LDPV + kq * 4] = pkv;
            }
        }
        if (tid < 64) padf[tid] = (mask[b * SS + kt0 + tid] == 0) ? 1.0f : 0.0f;
        __syncthreads();

        // S^T = K Q^T : C[kpos = i*16+quad*4+r][qrow = w*32+j*16+l15]
        f32x4 sc[4][2];
        #pragma unroll
        for (int i = 0; i < 4; ++i)
            #pragma unroll
            for (int j = 0; j < 2; ++j) sc[i][j] = (f32x4)(0.0f);
        #pragma unroll
        for (int ks = 0; ks < 2; ++ks) {
            bf16x8 aK[4];
            #pragma unroll
            for (int i = 0; i < 4; ++i)
                aK[i] = *(const bf16x8*)&Ks[(i * 16 + l15) * LDP + ks * 32 + quad * 8];
            #pragma unroll
            for (int i = 0; i < 4; ++i)
                #pragma unroll
                for (int j = 0; j < 2; ++j)
                    sc[i][j] = __builtin_amdgcn_mfma_f32_16x16x32_bf16(aK[i], bQ[j][ks], sc[i][j], 0, 0, 0);
        }

        // pad flags per (i,r): broadcast reads (same addr across l15 lanes)
        float pf[4][4];
        #pragma unroll
        for (int i = 0; i < 4; ++i)
            #pragma unroll
            for (int r = 0; r < 4; ++r)
                pf[i][r] = padf[i * 16 + quad * 4 + r];

        // online softmax per qrow tile j (each lane owns one qrow per j)
        #pragma unroll
        for (int j = 0; j < 2; ++j) {
            const int qrow = q0 + w * 32 + j * 16 + l15;
            float mx = -1e9f;
            #pragma unroll
            for (int i = 0; i < 4; ++i) {
                #pragma unroll
                for (int r = 0; r < 4; ++r) {
                    const int kpg = kt0 + i * 16 + quad * 4 + r;
                    float s = sc[i][j][r] * scale;
                    const bool masked = (kpg > qrow) || (pf[i][r] != 0.f);
                    s = masked ? -1e9f : s;
                    sc[i][j][r] = s;
                    mx = fmaxf(mx, s);
                }
            }
            mx = fmaxf(mx, __shfl_xor(mx, 16, 64));
            mx = fmaxf(mx, __shfl_xor(mx, 32, 64));
            const float nm = fmaxf(m_run[j], mx);
            const float alpha = __expf(m_run[j] - nm);
            m_run[j] = nm;
            float rs = 0.f;
            #pragma unroll
            for (int i = 0; i < 4; ++i) {
                float p0 = __expf(sc[i][j][0] - nm);
                float p1 = __expf(sc[i][j][1] - nm);
                float p2 = __expf(sc[i][j][2] - nm);
                float p3 = __expf(sc[i][j][3] - nm);
                rs += (p0 + p1) + (p2 + p3);
                // P stored [qrow][kpos]; 4 consecutive kpos -> one b64 write
                *(ushort4*)&QPs[(w * 32 + j * 16 + l15) * LDP + i * 16 + quad * 4] = pk4(p0, p1, p2, p3);
            }
            l_run[j] = l_run[j] * alpha + rs;
            #pragma unroll
            for (int i = 0; i < 4; ++i)
                #pragma unroll
                for (int r = 0; r < 4; ++r) o[i][j][r] *= alpha;
        }
        // same-wave LDS RAW (QPs writes -> bP reads): drain lgkm
        asm volatile("s_waitcnt lgkmcnt(0)" ::: "memory");

        // O^T += V^T P^T : A = Vs[hd][kpos], B = QPs[qrow][kpos]
        #pragma unroll
        for (int ks = 0; ks < 2; ++ks) {
            bf16x8 aV[4], bP[2];
            #pragma unroll
            for (int i = 0; i < 4; ++i)
                aV[i] = *(const bf16x8*)&Vs[(i * 16 + l15) * LDPV + ks * 32 + quad * 8];
            #pragma unroll
            for (int j = 0; j < 2; ++j)
                bP[j] = *(const bf16x8*)&QPs[(w * 32 + j * 16 + l15) * LDP + ks * 32 + quad * 8];
            #pragma unroll
            for (int i = 0; i < 4; ++i)
                #pragma unroll
                for (int j = 0; j < 2; ++j)
                    o[i][j] = __builtin_amdgcn_mfma_f32_16x16x32_bf16(aV[i], bP[j], o[i][j], 0, 0, 0);
        }
    }

    // final l reduction across quads, then store O^T -> AO [B,S,H*HD] (bf16)
    #pragma unroll
    for (int j = 0; j < 2; ++j) {
        float l = l_run[j];
        l += __shfl_xor(l, 16, 64);
        l += __shfl_xor(l, 32, 64);
        const float inv = (l > 0.f) ? (1.f / l) : 0.f;
        const int s = q0 + w * 32 + j * 16 + l15;
        const size_t rb = ((size_t)(b * SS + s)) * DD + h * HDD;
        #pragma unroll
        for (int i = 0; i < 4; ++i) {
            // 4 consecutive hd per lane -> one 8B store
            *(ushort4*)&AO[rb + i * 16 + quad * 4] =
                pk4(o[i][j][0] * inv, o[i][j][1] * inv, o[i][j][2] * inv, o[i][j][3] * inv);
        }
    }
}

extern "C" void kernel_launch(void* const* d_in, const int* in_sizes, int n_in,
                              void* d_out, int out_size, void* d_ws, size_t ws_size,
                              hipStream_t stream)
{
    const float* x  = (const float*)d_in[0];
    const int* mask = (const int*)d_in[1];
    const float* Wq = (const float*)d_in[2];
    const float* bq = (const float*)d_in[3];
    const float* Wk = (const float*)d_in[4];
    const float* bk = (const float*)d_in[5];
    const float* Wv = (const float*)d_in[6];
    const float* bv = (const float*)d_in[7];
    const float* Wo = (const float*)d_in[8];
    const float* bo = (const float*)d_in[9];
    float* out = (float*)d_out;

    u16* ws = (u16*)d_ws;
    const size_t NE = (size_t)MM * DD;            // 8388608 elems per [M,D] bf16 buffer
    if (ws_size < 4 * NE * sizeof(u16)) return;   // guard (proven not to fire)

    u16* Qb = ws;
    u16* Kb = ws + NE;
    u16* Vb = ws + 2 * NE;
    u16* Ab = ws + 3 * NE;   // x_bf16 first, then attention output (sequential reuse)

    dim3 blk(256);
    cvt_k<<<dim3(NE / 2048), blk, 0, stream>>>(x, Ab);
    gemm_qkv_k<<<dim3(MM / 128, DD / 128, 3), blk, 0, stream>>>(
        Ab, Wq, bq, Wk, bk, Wv, bv, Qb, Kb, Vb);
    attn_k<<<dim3(SS / QT, BB * HH), blk, 0, stream>>>(Qb, Kb, Vb, mask, Ab);
    gemm_out_k<<<dim3(MM / 128, DD / 128), blk, 0, stream>>>(Ab, Wo, bo, out);
}